// Round 5
// baseline (299.184 us; speedup 1.0000x reference)
//
#include <hip/hip_runtime.h>
#include <hip/hip_bf16.h>

// B=64, C=1, H=W=1024, KS=16, F=128, OUT=10, L=4096, K=256
#define B_    64
#define F_    128
#define L_    4096
#define K_    256
#define OUT_  10
#define HW_   (1024 * 1024)
#define WIMG_ 1024

typedef __attribute__((ext_vector_type(8))) short bf16x8;           // MFMA A/B frag
typedef __attribute__((ext_vector_type(4))) float f32x4;            // MFMA C/D frag
typedef __attribute__((ext_vector_type(8))) unsigned short u16x8;   // 16B LDS store

static __device__ __forceinline__ unsigned short f2bf(float f) {
    return __builtin_bit_cast(unsigned short, __float2bfloat16(f));
}
static __device__ __forceinline__ bf16x8 cvt8(float4 a, float4 b) {
    bf16x8 r;
    r[0] = (short)f2bf(a.x); r[1] = (short)f2bf(a.y);
    r[2] = (short)f2bf(a.z); r[3] = (short)f2bf(a.w);
    r[4] = (short)f2bf(b.x); r[5] = (short)f2bf(b.y);
    r[6] = (short)f2bf(b.z); r[7] = (short)f2bf(b.w);
    return r;
}

// ---------------------------------------------------------------------------
// One block per l, 512 threads = 8 waves; wave wc owns f in [wc*16, wc*16+16).
//   acc[m] (m = 4 b-tiles of 16) via mfma_f32_16x16x32_bf16, n-dim = 1.
// w path: global -> regs -> bf16 -> B-frag directly (layout match, no LDS).
// x path: 64b x 256k tile staged once to LDS bf16 (XOR-swizzled), ONE barrier.
// Target: VGPR <= 64 (launch_bounds(512,8)) -> 32 waves/CU; LDS 40960B -> 4 blk/CU.
// ---------------------------------------------------------------------------
__global__ __launch_bounds__(512, 8)
void lcn_main(const float* __restrict__ x, const float* __restrict__ wgt,
              const float* __restrict__ bias, const float* __restrict__ dec_w,
              float* __restrict__ ws) {
    const int l  = blockIdx.x;
    const int hb = l >> 6, wb = l & 63;
    const int t  = threadIdx.x;
    const int lane = t & 63;
    const int wc   = t >> 6;        // wave id = f-sixteenth
    const int ln15 = lane & 15;
    const int kg   = lane >> 4;     // k-subgroup 0..3

    __shared__ union {
        unsigned short xs[B_ * K_];  // 32 KB bf16, swizzled (k ^= (b&7)<<3)
        float ysm[B_][132];          // 33.8 KB (after main loop)
        float red[16][B_][OUT_];     // 40 KB   (after ysm reads)
    } u;

    // ---- stage x: thread b = t>>3, jl = t&7; 4 chunks of 8 k's ----
    {
        const int b  = t >> 3;
        const int jl = t & 7;
        const float* xp = x + (size_t)b * HW_ + (size_t)(hb * 16) * WIMG_ + wb * 16;
        const int swz = (b & 7) << 3;
        #pragma unroll
        for (int c = 0; c < 4; ++c) {
            const int k0  = c * 64 + jl * 8;
            const int row = k0 >> 4, col = k0 & 15;
            float4 v0 = *reinterpret_cast<const float4*>(xp + (size_t)row * WIMG_ + col);
            float4 v1 = *reinterpret_cast<const float4*>(xp + (size_t)row * WIMG_ + col + 4);
            bf16x8 s8 = cvt8(v0, v1);
            *reinterpret_cast<bf16x8*>(&u.xs[b * K_ + (k0 ^ swz)]) = s8;
        }
    }
    __syncthreads();   // the ONLY barrier before the epilogue

    // ---- main loop: stream this wave's 16 w-rows from global ----
    const float* wp = wgt + ((size_t)(wc * 16 + ln15) * L_ + l) * K_;

    f32x4 acc[4];
    #pragma unroll
    for (int m = 0; m < 4; ++m) acc[m] = (f32x4){0.f, 0.f, 0.f, 0.f};

    #pragma unroll
    for (int ks = 0; ks < 8; ++ks) {
        const int kb = ks * 32 + kg * 8;
        const float4 w0 = *reinterpret_cast<const float4*>(wp + kb);
        const float4 w1 = *reinterpret_cast<const float4*>(wp + kb + 4);
        const bf16x8 bw = cvt8(w0, w1);
        bf16x8 a[4];
        #pragma unroll
        for (int m = 0; m < 4; ++m) {
            const int b = m * 16 + ln15;
            a[m] = *reinterpret_cast<const bf16x8*>(
                &u.xs[b * K_ + (kb ^ ((b & 7) << 3))]);
        }
        #pragma unroll
        for (int m = 0; m < 4; ++m)
            acc[m] = __builtin_amdgcn_mfma_f32_16x16x32_bf16(a[m], bw, acc[m], 0, 0, 0);
    }

    // ---- epilogue: bias + ReLU -> ysm ----
    const float bv = bias[(size_t)(wc * 16 + ln15) * L_ + l];

    __syncthreads();   // all waves done reading xs before ysm overwrites it

    #pragma unroll
    for (int m = 0; m < 4; ++m)
        #pragma unroll
        for (int r = 0; r < 4; ++r) {
            const int b = m * 16 + kg * 4 + r;   // C/D: row = (lane>>4)*4+reg
            const int f = wc * 16 + ln15;        // C/D: col = lane&15
            u.ysm[b][f] = fmaxf(acc[m][r] + bv, 0.f);
        }
    __syncthreads();

    // ---- fused decoder: o split across thread halves; (tx,ty) owns 4b x 8f ----
    const int tt = t & 255;
    const int oh = t >> 8;              // 0: o 0..4, 1: o 5..9
    const int tx = tt & 15, ty = tt >> 4;
    const int b0_ = tx * 4, f0_ = ty * 8;

    float yv[4][8];
    #pragma unroll
    for (int bi = 0; bi < 4; ++bi) {
        f32x4 p0 = *reinterpret_cast<const f32x4*>(&u.ysm[b0_ + bi][f0_]);
        f32x4 p1 = *reinterpret_cast<const f32x4*>(&u.ysm[b0_ + bi][f0_ + 4]);
        yv[bi][0] = p0.x; yv[bi][1] = p0.y; yv[bi][2] = p0.z; yv[bi][3] = p0.w;
        yv[bi][4] = p1.x; yv[bi][5] = p1.y; yv[bi][6] = p1.z; yv[bi][7] = p1.w;
    }
    __syncthreads();   // ysm reads done before red overwrites the union

    float part[4][5];
    #pragma unroll
    for (int bi = 0; bi < 4; ++bi)
        #pragma unroll
        for (int oo = 0; oo < 5; ++oo) part[bi][oo] = 0.f;

    #pragma unroll
    for (int fj = 0; fj < 8; ++fj) {
        #pragma unroll
        for (int oo = 0; oo < 5; ++oo) {
            const int o = oh * 5 + oo;
            const float dw = dec_w[(size_t)o * ((size_t)F_ * L_) + (size_t)(f0_ + fj) * L_ + l];
            #pragma unroll
            for (int bi = 0; bi < 4; ++bi)
                part[bi][oo] = fmaf(yv[bi][fj], dw, part[bi][oo]);
        }
    }

    #pragma unroll
    for (int bi = 0; bi < 4; ++bi)
        #pragma unroll
        for (int oo = 0; oo < 5; ++oo)
            u.red[ty][b0_ + bi][oh * 5 + oo] = part[bi][oo];
    __syncthreads();

    for (int idx = t; idx < B_ * OUT_; idx += 512) {
        const int b = idx / OUT_;
        const int o = idx - b * OUT_;
        float s = 0.f;
        #pragma unroll
        for (int g = 0; g < 16; ++g) s += u.red[g][b][o];
        ws[(size_t)b * ((size_t)L_ * OUT_) + (size_t)l * OUT_ + o] = s;
    }
}

// ---------------------------------------------------------------------------
// Kernel B: reduce ws over l, add dec_b.
// ---------------------------------------------------------------------------
__global__ __launch_bounds__(640)
void lcn_reduce(const float* __restrict__ ws, const float* __restrict__ dec_b,
                float* __restrict__ out) {
    const int b = blockIdx.x;
    const int j = threadIdx.x;            // 0..639
    const float* base = ws + (size_t)b * ((size_t)L_ * OUT_);

    float s = 0.f;
    #pragma unroll 8
    for (int i = 0; i < 64; ++i)
        s += base[j + i * (64 * OUT_)];

    __shared__ float lds[64 * OUT_];
    lds[j] = s;
    __syncthreads();

    if (j < OUT_) {
        float tot = dec_b[j];
        #pragma unroll
        for (int lc = 0; lc < 64; ++lc) tot += lds[lc * OUT_ + j];
        out[b * OUT_ + j] = tot;
    }
}

extern "C" void kernel_launch(void* const* d_in, const int* in_sizes, int n_in,
                              void* d_out, int out_size, void* d_ws, size_t ws_size,
                              hipStream_t stream) {
    const float* x     = (const float*)d_in[0];
    const float* wgt   = (const float*)d_in[1];
    const float* bias  = (const float*)d_in[2];
    const float* dec_w = (const float*)d_in[3];
    const float* dec_b = (const float*)d_in[4];
    float* out = (float*)d_out;
    float* wsf = (float*)d_ws;   // 64*4096*10*4 = 10.49 MB

    lcn_main<<<dim3(L_), dim3(512), 0, stream>>>(x, wgt, bias, dec_w, wsf);
    lcn_reduce<<<dim3(B_), dim3(640), 0, stream>>>(wsf, dec_b, out);
}